// Round 1
// baseline (465.149 us; speedup 1.0000x reference)
//
#include <hip/hip_runtime.h>
#include <stdint.h>

typedef __bf16 bf16x8_t __attribute__((ext_vector_type(8)));
typedef float f32x4_t __attribute__((ext_vector_type(4)));
typedef uint16_t u16x8_t __attribute__((ext_vector_type(8)));

#define MFMA16(a, b, c) __builtin_amdgcn_mfma_f32_16x16x32_bf16((a), (b), (c), 0, 0, 0)

__device__ __forceinline__ void gll16(const void* g, void* l) {
  typedef const __attribute__((address_space(1))) void* gp1_t;
  typedef __attribute__((address_space(3))) void* lp3_t;
  __builtin_amdgcn_global_load_lds((gp1_t)(uintptr_t)g,
                                   (lp3_t)(uint32_t)(uintptr_t)l, 16, 0, 0);
}

__device__ __forceinline__ uint16_t f2bf(float f) {
  uint32_t u = __float_as_uint(f);
  u += 0x7fffu + ((u >> 16) & 1u);
  return (uint16_t)(u >> 16);
}

// ----------------------------- fp32 -> bf16 convert -----------------------------
__global__ __launch_bounds__(256) void cvt_kernel(const float* __restrict__ in,
                                                  uint16_t* __restrict__ out, int n8) {
  int i = blockIdx.x * 256 + threadIdx.x;
  if (i >= n8) return;
  const float4* p = (const float4*)in;
  float4 a = p[2 * i], b = p[2 * i + 1];
  u16x8_t v;
  v[0] = f2bf(a.x); v[1] = f2bf(a.y); v[2] = f2bf(a.z); v[3] = f2bf(a.w);
  v[4] = f2bf(b.x); v[5] = f2bf(b.y); v[6] = f2bf(b.z); v[7] = f2bf(b.w);
  ((u16x8_t*)out)[i] = v;
}

// ----------------------------- bf16 NT GEMM: C = A * Bw^T + bias -----------------------------
// A: [8192][1024] bf16 row-major, Bw: [1024][1024] bf16 row-major (N x K), C: [8192][1024]
// 128x128 tile, BK=64, 4 waves (2x2), 16x16x32 MFMA, XOR-swizzled LDS, global_load_lds staging.
template <bool BF16OUT>
__global__ __launch_bounds__(256) void gemm_bt_kernel(const uint16_t* __restrict__ A,
                                                      const uint16_t* __restrict__ Bw,
                                                      const float* __restrict__ bias,
                                                      void* __restrict__ C) {
  constexpr int K = 1024, N = 1024;
  __shared__ uint16_t As[128 * 64];
  __shared__ uint16_t Bs[128 * 64];
  char* AsB = (char*)As;
  char* BsB = (char*)Bs;
  const int tid = threadIdx.x;
  const int w = tid >> 6, l = tid & 63;
  const int wr = w >> 1, wc = w & 1;
  const int lrow = l & 15, g = l >> 4;
  const int bm0 = blockIdx.y * 128, bn0 = blockIdx.x * 128;
  // staging: lane l sources row (rbase + l>>3), swizzled col bytes
  const int srow = l >> 3;
  const int scb = ((l & 7) ^ srow) << 4;
  const char* Ab = (const char*)A;
  const char* Bb = (const char*)Bw;
  f32x4_t acc[4][4] = {};

  for (int it = 0; it < K / 64; ++it) {
    const int k0 = it * 64;
    __syncthreads();  // protect As/Bs from previous iteration readers
#pragma unroll
    for (int s = 0; s < 4; ++s) {
      const int rbase = s * 32 + w * 8;
      gll16(Ab + (size_t)(bm0 + rbase + srow) * (K * 2) + k0 * 2 + scb, AsB + rbase * 128);
      gll16(Bb + (size_t)(bn0 + rbase + srow) * (K * 2) + k0 * 2 + scb, BsB + rbase * 128);
    }
    asm volatile("s_waitcnt vmcnt(0)" ::: "memory");
    __syncthreads();
#pragma unroll
    for (int kk = 0; kk < 2; ++kk) {
      bf16x8_t af[4], bfr[4];
#pragma unroll
      for (int f = 0; f < 4; ++f) {
        const int ar = wr * 64 + f * 16 + lrow;
        af[f] = *(const bf16x8_t*)(AsB + ar * 128 + ((kk * 64 + g * 16) ^ ((ar & 7) << 4)));
        const int br = wc * 64 + f * 16 + lrow;
        bfr[f] = *(const bf16x8_t*)(BsB + br * 128 + ((kk * 64 + g * 16) ^ ((br & 7) << 4)));
      }
#pragma unroll
      for (int fm = 0; fm < 4; ++fm)
#pragma unroll
        for (int fn = 0; fn < 4; ++fn)
          acc[fm][fn] = MFMA16(af[fm], bfr[fn], acc[fm][fn]);
    }
  }
  // epilogue: C/D layout col = lane&15, row = (lane>>4)*4 + reg
#pragma unroll
  for (int fn = 0; fn < 4; ++fn) {
    const int col = bn0 + wc * 64 + fn * 16 + lrow;
    const float bv = bias[col];
#pragma unroll
    for (int fm = 0; fm < 4; ++fm) {
      const int row0 = bm0 + wr * 64 + fm * 16 + g * 4;
#pragma unroll
      for (int r = 0; r < 4; ++r) {
        const float v = acc[fm][fn][r] + bv;
        if (BF16OUT)
          ((uint16_t*)C)[(size_t)(row0 + r) * N + col] = f2bf(v);
        else
          ((float*)C)[(size_t)(row0 + r) * N + col] = v;
      }
    }
  }
}

// ----------------------------- flash attention (bf16, HD=64) -----------------------------
// grid: (16 q-tiles, 64 b*h). block: 256 threads = 4 waves, each wave owns 32 q rows.
// KV tile = 64. Online softmax. Q/K/V: [8192][1024] bf16 ws, head h occupies cols h*64..h*64+63.
__global__ __launch_bounds__(256) void attn_kernel(const uint16_t* __restrict__ Q,
                                                   const uint16_t* __restrict__ K,
                                                   const uint16_t* __restrict__ V,
                                                   uint16_t* __restrict__ AO) {
  constexpr int S = 2048, D = 1024;
  __shared__ uint16_t Ks[64 * 64];
  __shared__ uint16_t Vr[64 * 64];
  __shared__ uint16_t Vt[64 * 64];      // V^T: rows = head dim d (64), cols = t (64)
  __shared__ uint16_t Ps[4 * 32 * 64];  // per-wave P tile [32 r][64 t]
  char* KsB = (char*)Ks;
  char* VrB = (char*)Vr;
  char* VtB = (char*)Vt;
  char* PsB = (char*)Ps;
  const int tid = threadIdx.x;
  const int w = tid >> 6, l = tid & 63;
  const int lrow = l & 15, g = l >> 4;
  const int bh = blockIdx.y, b = bh >> 4, h = bh & 15;
  const int q0 = blockIdx.x * 128;
  const int srow = l >> 3;
  const int scb = ((l & 7) ^ srow) << 4;
  const char* Qb = (const char*)Q;
  const char* Kb = (const char*)K;
  const char* Vb = (const char*)V;

  // hoist Q fragments (A-operand): rows w*32 + fm*16 + lrow, k = kk*32 + g*8 .. +8
  bf16x8_t qf[2][2];
#pragma unroll
  for (int fm = 0; fm < 2; ++fm)
#pragma unroll
    for (int kk = 0; kk < 2; ++kk)
      qf[fm][kk] = *(const bf16x8_t*)(Qb + (size_t)(b * S + q0 + w * 32 + fm * 16 + lrow) * (D * 2) +
                                      h * 128 + kk * 64 + g * 16);

  float m_run[8], l_run[8];
#pragma unroll
  for (int i = 0; i < 8; ++i) {
    m_run[i] = -1e30f;
    l_run[i] = 0.f;
  }
  f32x4_t acco[2][4] = {};

  for (int t = 0; t < S / 64; ++t) {
    const int t0 = t * 64;
#pragma unroll
    for (int s = 0; s < 2; ++s) {
      const int rbase = s * 32 + w * 8;
      const size_t grow = (size_t)(b * S + t0 + rbase + srow);
      gll16(Kb + grow * (D * 2) + h * 128 + scb, KsB + rbase * 128);
      gll16(Vb + grow * (D * 2) + h * 128 + scb, VrB + rbase * 128);
    }
    asm volatile("s_waitcnt vmcnt(0)" ::: "memory");
    __syncthreads();

    // V transpose bounce: Vr[t][d] -> Vt[d][t]
#pragma unroll
    for (int ps = 0; ps < 2; ++ps) {
      const int slot = ps * 256 + tid;
      const int d = slot & 63, tt0 = (slot >> 6) * 8;
      u16x8_t vv;
#pragma unroll
      for (int j = 0; j < 8; ++j) {
        const int tr = tt0 + j;
        vv[j] = *(const uint16_t*)(VrB + tr * 128 + ((2 * d) ^ ((tr & 7) << 4)));
      }
      *(u16x8_t*)(VtB + d * 128 + ((2 * tt0) ^ ((d & 7) << 4))) = vv;
    }

    // QK^T: S[r, t] fragments (D rows = q rows, cols = kv t)
    f32x4_t sacc[2][4] = {};
#pragma unroll
    for (int kk = 0; kk < 2; ++kk)
#pragma unroll
      for (int fn = 0; fn < 4; ++fn) {
        const int kr = fn * 16 + lrow;
        bf16x8_t kf = *(const bf16x8_t*)(KsB + kr * 128 + ((kk * 64 + g * 16) ^ ((kr & 7) << 4)));
        sacc[0][fn] = MFMA16(qf[0][kk], kf, sacc[0][fn]);
        sacc[1][fn] = MFMA16(qf[1][kk], kf, sacc[1][fn]);
      }

    // online softmax (scale 1/sqrt(64) = 0.125). Row of slot (fm,r) lives in this lane's
    // 16-lane group; reduce over l&15 via shfl_xor 1,2,4,8.
#pragma unroll
    for (int fm = 0; fm < 2; ++fm)
#pragma unroll
      for (int r = 0; r < 4; ++r) {
        float mx = fmaxf(fmaxf(sacc[fm][0][r], sacc[fm][1][r]),
                         fmaxf(sacc[fm][2][r], sacc[fm][3][r]));
#pragma unroll
        for (int dd = 1; dd < 16; dd <<= 1) mx = fmaxf(mx, __shfl_xor(mx, dd));
        mx *= 0.125f;
        const int slot = fm * 4 + r;
        const float mold = m_run[slot];
        const float mnew = fmaxf(mold, mx);
        const float sc = __expf(mold - mnew);
        m_run[slot] = mnew;
        float rs = 0.f;
#pragma unroll
        for (int fn = 0; fn < 4; ++fn) {
          const float p = __expf(sacc[fm][fn][r] * 0.125f - mnew);
          sacc[fm][fn][r] = p;
          rs += p;
        }
#pragma unroll
        for (int dd = 1; dd < 16; dd <<= 1) rs += __shfl_xor(rs, dd);
        l_run[slot] = l_run[slot] * sc + rs;
#pragma unroll
        for (int fd = 0; fd < 4; ++fd) acco[fm][fd][r] *= sc;
      }

    // write P (bf16) to per-wave LDS tile [32 r][64 t], swizzled
#pragma unroll
    for (int fm = 0; fm < 2; ++fm)
#pragma unroll
      for (int fn = 0; fn < 4; ++fn)
#pragma unroll
        for (int r = 0; r < 4; ++r) {
          const int rloc = fm * 16 + g * 4 + r;
          const int tt = fn * 16 + lrow;
          *(uint16_t*)(PsB + w * 4096 + rloc * 128 + ((2 * tt) ^ ((rloc & 7) << 4))) =
              f2bf(sacc[fm][fn][r]);
        }

    __syncthreads();  // Vt (cross-wave) + P visibility

    // PV: O[r, d] += P[r, t] * V[t, d]  (A = P rows r, B = Vt rows d)
#pragma unroll
    for (int kk = 0; kk < 2; ++kk) {
      bf16x8_t pf[2];
#pragma unroll
      for (int fm = 0; fm < 2; ++fm) {
        const int pr = fm * 16 + lrow;
        pf[fm] = *(const bf16x8_t*)(PsB + w * 4096 + pr * 128 +
                                    ((kk * 64 + g * 16) ^ ((pr & 7) << 4)));
      }
#pragma unroll
      for (int fd = 0; fd < 4; ++fd) {
        const int vr = fd * 16 + lrow;
        bf16x8_t vf = *(const bf16x8_t*)(VtB + vr * 128 + ((kk * 64 + g * 16) ^ ((vr & 7) << 4)));
        acco[0][fd] = MFMA16(pf[0], vf, acco[0][fd]);
        acco[1][fd] = MFMA16(pf[1], vf, acco[1][fd]);
      }
    }
  }

  // epilogue: O /= l, write bf16 to AO
#pragma unroll
  for (int fm = 0; fm < 2; ++fm)
#pragma unroll
    for (int r = 0; r < 4; ++r) {
      const float inv = 1.0f / l_run[fm * 4 + r];
      const size_t row = (size_t)(b * S + q0 + w * 32 + fm * 16 + g * 4 + r);
#pragma unroll
      for (int fd = 0; fd < 4; ++fd)
        AO[row * D + h * 64 + fd * 16 + lrow] = f2bf(acco[fm][fd][r] * inv);
    }
}

// ----------------------------- launch -----------------------------
extern "C" void kernel_launch(void* const* d_in, const int* in_sizes, int n_in,
                              void* d_out, int out_size, void* d_ws, size_t ws_size,
                              hipStream_t stream) {
  const float* q_in = (const float*)d_in[0];
  const float* k_in = (const float*)d_in[1];
  const float* v_in = (const float*)d_in[2];
  const float* Wq = (const float*)d_in[3];
  const float* bq = (const float*)d_in[4];
  const float* Wk = (const float*)d_in[5];
  const float* bk = (const float*)d_in[6];
  const float* Wv = (const float*)d_in[7];
  const float* bv = (const float*)d_in[8];
  const float* Wo = (const float*)d_in[9];
  const float* bo = (const float*)d_in[10];

  const size_t MD = (size_t)8192 * 1024;
  const size_t DD = (size_t)1024 * 1024;
  uint16_t* Xq = (uint16_t*)d_ws;
  uint16_t* Xk = Xq + MD;
  uint16_t* Xv = Xk + MD;
  uint16_t* Wqb = Xv + MD;
  uint16_t* Wkb = Wqb + DD;
  uint16_t* Wvb = Wkb + DD;
  uint16_t* Wob = Wvb + DD;
  uint16_t* Qp = Wob + DD;
  uint16_t* Kp = Qp + MD;
  uint16_t* Vp = Kp + MD;
  uint16_t* AO = Xq;  // reuse Xq: only read by the Q projection, which completes before attn

  dim3 cb(256);
  cvt_kernel<<<4096, cb, 0, stream>>>(q_in, Xq, 1048576);
  cvt_kernel<<<4096, cb, 0, stream>>>(k_in, Xk, 1048576);
  cvt_kernel<<<4096, cb, 0, stream>>>(v_in, Xv, 1048576);
  cvt_kernel<<<512, cb, 0, stream>>>(Wq, Wqb, 131072);
  cvt_kernel<<<512, cb, 0, stream>>>(Wk, Wkb, 131072);
  cvt_kernel<<<512, cb, 0, stream>>>(Wv, Wvb, 131072);
  cvt_kernel<<<512, cb, 0, stream>>>(Wo, Wob, 131072);

  dim3 gg(8, 64), gb(256);
  gemm_bt_kernel<true><<<gg, gb, 0, stream>>>(Xq, Wqb, bq, Qp);
  gemm_bt_kernel<true><<<gg, gb, 0, stream>>>(Xk, Wkb, bk, Kp);
  gemm_bt_kernel<true><<<gg, gb, 0, stream>>>(Xv, Wvb, bv, Vp);

  attn_kernel<<<dim3(16, 64), gb, 0, stream>>>(Qp, Kp, Vp, AO);

  gemm_bt_kernel<false><<<gg, gb, 0, stream>>>(AO, Wob, bo, d_out);
}